// Round 1
// baseline (399.414 us; speedup 1.0000x reference)
//
#include <hip/hip_runtime.h>

#define NS 6
#define NXD 3
#define NC 8
#define NR 64
#define NB 36          // S * 2 * XD
#define NPOINTS 262144
#define OUTD 288       // C * NB
#define PTS 32         // points per block

__device__ __forceinline__ unsigned short f2bf(float f) {
    unsigned u = __float_as_uint(f);
    unsigned r = u + 0x7fffu + ((u >> 16) & 1u);   // round-to-nearest-even
    return (unsigned short)(r >> 16);
}
__device__ __forceinline__ unsigned pack2(float a, float b) {
    return (unsigned)f2bf(a) | ((unsigned)f2bf(b) << 16);
}

// px: [NB][65][64][NC] uints; each uint = bf16 pair {F2[b][c][y][x], F2[b][c][y][min(x+1,63)]}
// row 64 replicates row 63 (y1=y0+1 can reach 64 with weight 0)
__global__ void build_px(const float* __restrict__ F2, unsigned* __restrict__ px) {
    int tid = blockIdx.x * 256 + threadIdx.x;
    const int total = NB * 65 * 64 * NC;
    if (tid >= total) return;
    int c = tid & 7;
    int xx = (tid >> 3) & 63;
    int rest = tid >> 9;          // b*65 + y
    int y = rest % 65;
    int b = rest / 65;
    int ys = y < 63 ? y : 63;
    const float* src = F2 + (((size_t)(b * NC + c) * NR + ys) * NR);
    float v0 = src[xx];
    float v1 = src[xx < 63 ? xx + 1 : 63];
    px[tid] = pack2(v0, v1);
}

// f1q: [NB][64][NC] uints; uint = bf16 pair {f1[y], f1[min(y+1,63)]},
// f1[y] = 0.5*(F[b][c][y][31] + F[b][c][y][32])   (gx=0 => wx=0.5 exactly)
__global__ void build_f1q(const float* __restrict__ F, unsigned* __restrict__ f1q) {
    int tid = blockIdx.x * 256 + threadIdx.x;
    const int total = NB * 64 * NC;
    if (tid >= total) return;
    int c = tid & 7;
    int y = (tid >> 3) & 63;
    int b = tid >> 9;
    const float* img = F + (size_t)(b * NC + c) * NR * NR;
    float a = 0.5f * (img[y * NR + 31] + img[y * NR + 32]);
    int y1 = y < 63 ? y + 1 : 63;
    float bb = 0.5f * (img[y1 * NR + 31] + img[y1 * NR + 32]);
    f1q[tid] = pack2(a, bb);
}

__global__ __launch_bounds__(256, 3) void encode_kernel(
    const float* __restrict__ x,
    const unsigned* __restrict__ px,
    const unsigned* __restrict__ f1q,
    float* __restrict__ out)
{
    __shared__ float lat[PTS][NB];        // 4.6 KB
    __shared__ float stage[PTS * 289];    // 36.1 KB, pad 289 -> 2-way bank alias (free)
    const int t = threadIdx.x;
    const int c = t & 7;                  // channel lane
    const int u = t >> 3;                 // point within tile
    const int n = blockIdx.x * PTS + u;

    const float xv0 = x[3 * n + 0];
    const float xv1 = x[3 * n + 1];
    const float xv2 = x[3 * n + 2];

    // cooperative latent: lat[u][i], i = s*6 + p*3 + d ; p=0 -> sin, p=1 -> cos
    #pragma unroll
    for (int ii = 0; ii < 5; ++ii) {
        int i = c + ii * 8;
        if (i < NB) {
            int s = i / 6;
            int rr = i - s * 6;
            int p = rr / 3;
            int d = rr - p * 3;
            float xb = (d == 0 ? xv0 : (d == 1 ? xv1 : xv2)) * (float)(1 << s);
            lat[u][i] = p ? __cosf(xb) : __sinf(xb);
        }
    }
    __syncthreads();

    const float* latu = lat[u];
    float* stg = &stage[u * 289];

    for (int g = 0; g < 12; ++g) {        // (s,p) groups
        const int b0 = g * 3;
        #pragma unroll
        for (int k = 0; k < 3; ++k) {
            const int b = b0 + k;
            const int i0 = b0 + (k == 0 ? 1 : (k == 1 ? 2 : 0));  // pairs[k][0]
            const int i1 = b0 + (k == 0 ? 2 : (k == 1 ? 0 : 1));  // pairs[k][1]
            float gy1 = latu[b];
            float ga = latu[i0];
            float gb = latu[i1];

            // fs: 1-D lerp (wx = 0.5 folded into f1q)
            float fy = fminf(fmaxf(__builtin_fmaf(gy1, 31.5f, 31.5f), 0.0f), 63.0f);
            float fy0 = floorf(fy);
            float wy = fy - fy0;
            int y0 = (int)fy0;
            unsigned pr = f1q[(b * 64 + y0) * 8 + c];
            float a0 = __uint_as_float(pr << 16);
            float a1 = __uint_as_float(pr & 0xffff0000u);
            float fsv = __builtin_fmaf(a1 - a0, wy, a0);

            // fs2: bilinear, x-pairs packed
            float fx2 = fminf(fmaxf(__builtin_fmaf(ga, 31.5f, 31.5f), 0.0f), 63.0f);
            float fy2 = fminf(fmaxf(__builtin_fmaf(gb, 31.5f, 31.5f), 0.0f), 63.0f);
            float fx20 = floorf(fx2);
            float fy20 = floorf(fy2);
            float wx2 = fx2 - fx20;
            float wy2 = fy2 - fy20;
            int xx = (int)fx20;
            int yy = (int)fy20;
            const unsigned* rb = px + ((b * 65 + yy) * 64 + xx) * 8 + c;
            unsigned top = rb[0];
            unsigned bot = rb[512];       // next y row: 64*8 uints
            float v00 = __uint_as_float(top << 16);
            float v01 = __uint_as_float(top & 0xffff0000u);
            float v10 = __uint_as_float(bot << 16);
            float v11 = __uint_as_float(bot & 0xffff0000u);
            float tp = __builtin_fmaf(v01 - v00, wx2, v00);
            float bt = __builtin_fmaf(v11 - v10, wx2, v10);
            float fs2v = __builtin_fmaf(bt - tp, wy2, tp);

            stg[c * 36 + b] = __builtin_fmaf(fsv, fs2v, gy1);
        }
    }
    __syncthreads();

    // coalesced writeback: block region = PTS*288 consecutive floats
    float* ob = out + (size_t)blockIdx.x * (PTS * OUTD);
    #pragma unroll
    for (int r = 0; r < 36; ++r) {
        int e = t + r * 256;
        int uu = e / 288;
        int v = e - uu * 288;
        ob[e] = stage[uu * 289 + v];
    }
}

extern "C" void kernel_launch(void* const* d_in, const int* in_sizes, int n_in,
                              void* d_out, int out_size, void* d_ws, size_t ws_size,
                              hipStream_t stream)
{
    const float* x  = (const float*)d_in[0];
    const float* F  = (const float*)d_in[1];
    const float* F2 = (const float*)d_in[2];
    float* out = (float*)d_out;

    unsigned* px  = (unsigned*)d_ws;                 // 1,198,080 uints = 4,792,320 B
    unsigned* f1q = px + NB * 65 * 64 * NC;          //    18,432 uints =    73,728 B

    build_px<<<(NB * 65 * 64 * NC + 255) / 256, 256, 0, stream>>>(F2, px);
    build_f1q<<<(NB * 64 * NC + 255) / 256, 256, 0, stream>>>(F, f1q);
    encode_kernel<<<NPOINTS / PTS, 256, 0, stream>>>(x, px, f1q, out);
}